// Round 6
// baseline (679.071 us; speedup 1.0000x reference)
//
#include <hip/hip_runtime.h>
#include <hip/hip_bf16.h>
#include <cstdint>
#include <cstddef>

// Problem constants
#define B_    4
#define N_    1024
#define CIN_  256
#define HW_   256      // H == W == 256
#define D_    512
#define INK_  2304     // CIN * PH * PW
#define BN_   4096     // B * N

// ATTRIBUTION ROUND: every fast-path kernel is launched TWICE (all are
// idempotent pure functions of their inputs). dur_us - 507 = total warm
// kernel time => separates fixed harness overhead from kernel cost.

typedef __attribute__((ext_vector_type(8))) short bf16x8;
typedef __attribute__((ext_vector_type(4))) float f32x4;
typedef __attribute__((ext_vector_type(4))) unsigned short us4;

#define AS1(p) ((const __attribute__((address_space(1))) void*)(p))
#define AS3(p) ((__attribute__((address_space(3))) void*)(p))

__device__ __forceinline__ unsigned short f2bf(float f) {
    union { float f; unsigned u; } v; v.f = f;
    unsigned r = v.u + 0x7fffu + ((v.u >> 16) & 1u);   // round-to-nearest-even
    return (unsigned short)(r >> 16);
}

// ---------------------------------------------------------------------------
// 64x64 tile transpose body: src fp32 (Mrows, Ncols) -> dst bf16 (Ncols, Mrows)
// ---------------------------------------------------------------------------
__device__ __forceinline__ void t64_body(
    const float* __restrict__ src, unsigned short* __restrict__ dst,
    int Mrows, int Ncols, int m0, int n0, int t,
    unsigned short (*tile)[66])
{
    const int rr = t >> 4;          // 0..15
    const int cc = t & 15;          // 0..15

    #pragma unroll
    for (int i = 0; i < 4; ++i) {
        int row = i * 16 + rr;
        float4 v = *(const float4*)(src + (size_t)(m0 + row) * Ncols + n0 + cc * 4);
        tile[row][cc * 4 + 0] = f2bf(v.x);
        tile[row][cc * 4 + 1] = f2bf(v.y);
        tile[row][cc * 4 + 2] = f2bf(v.z);
        tile[row][cc * 4 + 3] = f2bf(v.w);
    }
    __syncthreads();
    #pragma unroll
    for (int i = 0; i < 4; ++i) {
        int p = i * 16 + rr;
        unsigned short v0 = tile[cc * 4 + 0][p];
        unsigned short v1 = tile[cc * 4 + 1][p];
        unsigned short v2 = tile[cc * 4 + 2][p];
        unsigned short v3 = tile[cc * 4 + 3][p];
        unsigned short* dp = dst + (size_t)(n0 + p) * Mrows + m0 + cc * 4;
        *(us4*)dp = (us4){v0, v1, v2, v3};
    }
}

// feats (B,CIN,HW*HW) f32 -> featsT (B,HW*HW,CIN) bf16
__global__ __launch_bounds__(256) void k_t64f(
    const float* __restrict__ src, unsigned short* __restrict__ dst)
{
    __shared__ unsigned short tile[64][66];
    const size_t batch = (size_t)CIN_ * HW_ * HW_;
    t64_body(src + blockIdx.z * batch, dst + blockIdx.z * batch,
             CIN_, HW_ * HW_, blockIdx.y * 64, blockIdx.x * 64,
             threadIdx.x, tile);
}

// W1 (2304,512)->W1t (512,2304) and W2 (512,512)->W2t (512,512) in ONE launch.
__global__ __launch_bounds__(256) void k_t64w(
    const float* __restrict__ W1, const float* __restrict__ W2,
    unsigned short* __restrict__ W1t, unsigned short* __restrict__ W2t)
{
    __shared__ unsigned short tile[64][66];
    if (blockIdx.y < 36) {
        t64_body(W1, W1t, INK_, D_, blockIdx.y * 64, blockIdx.x * 64,
                 threadIdx.x, tile);
    } else {
        t64_body(W2, W2t, D_, D_, (blockIdx.y - 36) * 64, blockIdx.x * 64,
                 threadIdx.x, tile);
    }
}

// ---------------------------------------------------------------------------
// ROI-align gather (roi5): block = 2 boxes x 4 waves; sample-halves split
// across 32-lane halves, combined via __shfl_xor(.,32).
// ---------------------------------------------------------------------------
__global__ __launch_bounds__(256) void k_roi5(
    const unsigned short* __restrict__ featsT, const float* __restrict__ boxes,
    unsigned short* __restrict__ flat)
{
    __shared__ int   so[2][36][4];
    __shared__ float sw[2][36][4];
    const int t = threadIdx.x;

    if (t < 72) {
        const int mbx = t / 36, s = t - mbx * 36;
        const int mbn = blockIdx.x * 2 + mbx;
        const float* bx = boxes + (size_t)mbn * 8;
        float xmn = fminf(fminf(bx[0], bx[2]), fminf(bx[4], bx[6]));
        float xmx = fmaxf(fmaxf(bx[0], bx[2]), fmaxf(bx[4], bx[6]));
        float ymn = fminf(fminf(bx[1], bx[3]), fminf(bx[5], bx[7]));
        float ymx = fmaxf(fmaxf(bx[1], bx[3]), fmaxf(bx[5], bx[7]));
        float sx1 = xmn * 0.25f, sy1 = ymn * 0.25f;
        float sx2 = xmx * 0.25f, sy2 = ymx * 0.25f;
        float rw = fmaxf(sx2 - sx1, 1.0f), rh = fmaxf(sy2 - sy1, 1.0f);
        float binw = rw * (1.0f / 3.0f), binh = rh * (1.0f / 3.0f);
        int row = s / 6, col = s % 6;
        float y = sy1 + (row * 0.5f + 0.25f) * binh;
        float x = sx1 + (col * 0.5f + 0.25f) * binw;
        float valid = (y > -1.0f && y < 256.0f && x > -1.0f && x < 256.0f) ? 1.0f : 0.0f;
        y = fminf(fmaxf(y, 0.0f), 255.0f);
        x = fminf(fmaxf(x, 0.0f), 255.0f);
        int y0 = (int)floorf(y), x0 = (int)floorf(x);
        int y1 = min(y0 + 1, 255), x1 = min(x0 + 1, 255);
        float ly = y - (float)y0, lx = x - (float)x0;
        float hy = 1.0f - ly, hx = 1.0f - lx;
        float m = 0.25f * valid;
        so[mbx][s][0] = y0 * HW_ + x0;  so[mbx][s][1] = y0 * HW_ + x1;
        so[mbx][s][2] = y1 * HW_ + x0;  so[mbx][s][3] = y1 * HW_ + x1;
        sw[mbx][s][0] = hy * hx * m;    sw[mbx][s][1] = hy * lx * m;
        sw[mbx][s][2] = ly * hx * m;    sw[mbx][s][3] = ly * lx * m;
    }
    __syncthreads();

    const int w    = t >> 6;
    const int l    = t & 63;
    const int bxi  = w >> 1;
    const int half = w & 1;
    const int qd   = half * 32 + (l & 31);
    const int sh   = l >> 5;
    const int j0   = sh * 18;
    const int bn   = blockIdx.x * 2 + bxi;
    const int b    = bn >> 10;
    const uint2* basep = (const uint2*)featsT + (size_t)b * (65536ull * 64ull) + qd;

    float a0[9] = {0,0,0,0,0,0,0,0,0};
    float a1[9] = {0,0,0,0,0,0,0,0,0};
    float a2[9] = {0,0,0,0,0,0,0,0,0};
    float a3[9] = {0,0,0,0,0,0,0,0,0};
    #pragma unroll
    for (int jj = 0; jj < 18; ++jj) {
        const int j = j0 + jj;
        #pragma unroll
        for (int p = 0; p < 4; ++p) {
            float wgt = sw[bxi][j][p];
            uint2 u = basep[(size_t)so[bxi][j][p] << 6];
            const int binA = (( jj / 6      ) >> 1) * 3 + ((jj % 6) >> 1);  // sh=0
            const int binB = (((jj / 6) + 3 ) >> 1) * 3 + ((jj % 6) >> 1);  // sh=1
            const int bs = sh ? binB : binA;
            a0[bs] += wgt * __uint_as_float(u.x << 16);
            a1[bs] += wgt * __uint_as_float(u.x & 0xffff0000u);
            a2[bs] += wgt * __uint_as_float(u.y << 16);
            a3[bs] += wgt * __uint_as_float(u.y & 0xffff0000u);
        }
    }

    #pragma unroll
    for (int k = 0; k < 9; ++k) {
        a0[k] += __shfl_xor(a0[k], 32);
        a1[k] += __shfl_xor(a1[k], 32);
        a2[k] += __shfl_xor(a2[k], 32);
        a3[k] += __shfl_xor(a3[k], 32);
    }

    unsigned short lo9[9], hi9[9];
    #pragma unroll
    for (int k = 0; k < 9; ++k) {
        lo9[k] = f2bf(sh ? a2[k] : a0[k]);
        hi9[k] = f2bf(sh ? a3[k] : a1[k]);
    }
    unsigned short s18[18];
    #pragma unroll
    for (int k = 0; k < 9; ++k) { s18[k] = lo9[k]; s18[9 + k] = hi9[k]; }
    unsigned* dst = (unsigned*)(flat + (size_t)bn * INK_) + qd * 18 + sh * 9;
    #pragma unroll
    for (int k = 0; k < 9; ++k)
        dst[k] = (unsigned)s18[2 * k] | ((unsigned)s18[2 * k + 1] << 16);
}

// ---------------------------------------------------------------------------
// GEMM1: 64x64 tile, BK=32, global_load_lds dbuf, T2 chunk swizzle.
// ---------------------------------------------------------------------------
template <int K, bool RELU_BF16OUT>
__global__ __launch_bounds__(256) void k_gemmB64(
    const unsigned short* __restrict__ A,
    const unsigned short* __restrict__ Bt,
    const float* __restrict__ bias,
    unsigned short* __restrict__ Cbf,
    float* __restrict__ Cf)
{
    __shared__ __align__(16) unsigned short As[2][64 * 32];
    __shared__ __align__(16) unsigned short Bs[2][64 * 32];

    const int t = threadIdx.x;
    const int w = t >> 6;
    const int lane = t & 63;
    const int lane16 = lane & 15;
    const int q = lane >> 4;
    const int m0 = blockIdx.x * 64;
    const int n0 = blockIdx.y * 64;

    const int srow = t >> 2;
    const int c4s  = (t & 3) ^ ((t >> 4) & 3);
    const unsigned short* gA = A  + (size_t)(m0 + srow) * K + c4s * 8;
    const unsigned short* gB = Bt + (size_t)(n0 + srow) * K + c4s * 8;
    const int ldst = srow * 32 + (t & 3) * 8;

    const int qs = q ^ ((lane16 >> 2) & 3);

    f32x4 acc[4] = {};

    __builtin_amdgcn_global_load_lds(AS1(gA), AS3(&As[0][0] + ldst), 16, 0, 0);
    __builtin_amdgcn_global_load_lds(AS1(gB), AS3(&Bs[0][0] + ldst), 16, 0, 0);
    gA += 32; gB += 32;

    int cur = 0;
    for (int k0 = 0; k0 < K; k0 += 32) {
        __syncthreads();
        if (k0 + 32 < K) {
            __builtin_amdgcn_global_load_lds(AS1(gA), AS3(&As[cur ^ 1][0] + ldst), 16, 0, 0);
            __builtin_amdgcn_global_load_lds(AS1(gB), AS3(&Bs[cur ^ 1][0] + ldst), 16, 0, 0);
            gA += 32; gB += 32;
        }
        bf16x8 av = *(const bf16x8*)&As[cur][(w * 16 + lane16) * 32 + qs * 8];
        #pragma unroll
        for (int nt = 0; nt < 4; ++nt) {
            bf16x8 bv = *(const bf16x8*)&Bs[cur][(nt * 16 + lane16) * 32 + qs * 8];
            acc[nt] = __builtin_amdgcn_mfma_f32_16x16x32_bf16(av, bv, acc[nt], 0, 0, 0);
        }
        cur ^= 1;
    }

    #pragma unroll
    for (int nt = 0; nt < 4; ++nt) {
        int col = n0 + nt * 16 + lane16;
        float bs = bias[col];
        #pragma unroll
        for (int r = 0; r < 4; ++r) {
            int row = m0 + w * 16 + q * 4 + r;
            float v = acc[nt][r] + bs;
            if constexpr (RELU_BF16OUT) {
                v = fmaxf(v, 0.0f);
                Cbf[(size_t)row * D_ + col] = f2bf(v);
            } else {
                Cf[(size_t)row * D_ + col] = v;
            }
        }
    }
}

// ---------------------------------------------------------------------------
// Fused GEMM2 + bias + pos-matvec + LN1 + add + LN2 + transposed store + mask.
// ---------------------------------------------------------------------------
__global__ __launch_bounds__(256) void k_fuse2(
    const unsigned short* __restrict__ act,
    const unsigned short* __restrict__ W2t,
    const float* __restrict__ b2,
    const float* __restrict__ boxes,
    const float* __restrict__ img_sizes,
    const float* __restrict__ Wb,  const float* __restrict__ bbv,
    const float* __restrict__ g1,  const float* __restrict__ be1,
    const float* __restrict__ g2,  const float* __restrict__ be2,
    float* __restrict__ out)
{
    __shared__ float S2[16 * D_];    // 32 KB

    const int t = threadIdx.x;
    const int w = t >> 6, l = t & 63;
    const int lane16 = l & 15, q = l >> 4;
    const int m0 = blockIdx.x * 16;
    const int b  = m0 >> 10;

    f32x4 acc[8] = {};
    const unsigned short* gA = act + (size_t)(m0 + lane16) * D_ + q * 8;
    const unsigned short* gW = W2t + (size_t)(w * 128 + lane16) * D_ + q * 8;

    #pragma unroll 2
    for (int k0 = 0; k0 < D_; k0 += 32) {
        bf16x8 av = *(const bf16x8*)(gA + k0);
        #pragma unroll
        for (int nt = 0; nt < 8; ++nt) {
            bf16x8 bv = *(const bf16x8*)(gW + (size_t)(nt * 16) * D_ + k0);
            acc[nt] = __builtin_amdgcn_mfma_f32_16x16x32_bf16(av, bv, acc[nt], 0, 0, 0);
        }
    }

    #pragma unroll
    for (int nt = 0; nt < 8; ++nt) {
        int col = w * 128 + nt * 16 + lane16;
        float bs = b2[col];
        #pragma unroll
        for (int r = 0; r < 4; ++r)
            S2[(q * 4 + r) * D_ + col] = acc[nt][r] + bs;
    }
    __syncthreads();

    const float si0 = img_sizes[b * 2], si1 = img_sizes[b * 2 + 1];
    #pragma unroll 1
    for (int j = 0; j < 4; ++j) {
        const int rho = w * 4 + j;
        const float* bx = boxes + (size_t)(m0 + rho) * 8;
        float xmn = fminf(fminf(bx[0], bx[2]), fminf(bx[4], bx[6]));
        float xmx = fmaxf(fmaxf(bx[0], bx[2]), fmaxf(bx[4], bx[6]));
        float ymn = fminf(fminf(bx[1], bx[3]), fminf(bx[5], bx[7]));
        float ymx = fmaxf(fmaxf(bx[1], bx[3]), fmaxf(bx[5], bx[7]));
        float q0 = xmn / si0, q1 = ymn / si1, q2 = xmx / si0, q3 = ymx / si1;

        float tp[8], su = 0.f, sq = 0.f;
        #pragma unroll
        for (int i = 0; i < 8; ++i) {
            int d = i * 64 + l;
            float v = q0 * Wb[d] + q1 * Wb[512 + d] + q2 * Wb[1024 + d]
                    + q3 * Wb[1536 + d] + bbv[d];
            tp[i] = v; su += v; sq += v * v;
        }
        #pragma unroll
        for (int off = 32; off > 0; off >>= 1) {
            su += __shfl_xor(su, off); sq += __shfl_xor(sq, off);
        }
        float mu = su * (1.0f / 512.0f);
        float rs = rsqrtf(sq * (1.0f / 512.0f) - mu * mu + 1e-5f);

        float sv[8]; su = 0.f; sq = 0.f;
        #pragma unroll
        for (int i = 0; i < 8; ++i) {
            int d = i * 64 + l;
            float p = (tp[i] - mu) * rs * g1[d] + be1[d];
            float s = S2[rho * D_ + d] + p;
            sv[i] = s; su += s; sq += s * s;
        }
        #pragma unroll
        for (int off = 32; off > 0; off >>= 1) {
            su += __shfl_xor(su, off); sq += __shfl_xor(sq, off);
        }
        float mu2 = su * (1.0f / 512.0f);
        float rs2 = rsqrtf(sq * (1.0f / 512.0f) - mu2 * mu2 + 1e-5f);

        #pragma unroll
        for (int i = 0; i < 8; ++i) {
            int d = i * 64 + l;
            S2[rho * D_ + d] = (sv[i] - mu2) * rs2 * g2[d] + be2[d];
        }
    }
    __syncthreads();

    const int nb = m0 & 1023;
    float* ob = out + (size_t)b * (D_ * N_) + nb;
    const int dd = t >> 2, part = t & 3;
    #pragma unroll
    for (int i = 0; i < 8; ++i) {
        int d = i * 64 + dd;
        float4 v;
        v.x = S2[(part * 4 + 0) * D_ + d];
        v.y = S2[(part * 4 + 1) * D_ + d];
        v.z = S2[(part * 4 + 2) * D_ + d];
        v.w = S2[(part * 4 + 3) * D_ + d];
        *(float4*)(ob + (size_t)d * N_ + part * 4) = v;
    }
    if (t < 16) out[(size_t)B_ * D_ * N_ + m0 + t] = 1.0f;   // masks
}

// ---------------------------------------------------------------------------
// FALLBACK path kernels (unchanged).
// ---------------------------------------------------------------------------
__global__ __launch_bounds__(256) void k_convert(
    const float* __restrict__ W1, const float* __restrict__ W2,
    unsigned short* __restrict__ W1t, unsigned short* __restrict__ W2t)
{
    int i = blockIdx.x * 256 + threadIdx.x;
    const int n1 = INK_ * D_;
    if (i < n1) {
        int n = i / INK_, k = i % INK_;
        W1t[i] = f2bf(W1[(size_t)k * D_ + n]);
    } else {
        int j = i - n1;
        if (j < D_ * D_) {
            int n = j / D_, k = j % D_;
            W2t[j] = f2bf(W2[(size_t)k * D_ + n]);
        }
    }
}

__global__ __launch_bounds__(256) void k_roi(
    const float* __restrict__ feats, const float* __restrict__ boxes,
    unsigned short* __restrict__ flat)
{
    __shared__ int   so[36][4];
    __shared__ float sw[36][4];
    const int bn = blockIdx.x;
    const int b  = bn >> 10;
    const int t  = threadIdx.x;

    if (t < 36) {
        const float* bx = boxes + (size_t)bn * 8;
        float xmn = fminf(fminf(bx[0], bx[2]), fminf(bx[4], bx[6]));
        float xmx = fmaxf(fmaxf(bx[0], bx[2]), fmaxf(bx[4], bx[6]));
        float ymn = fminf(fminf(bx[1], bx[3]), fminf(bx[5], bx[7]));
        float ymx = fmaxf(fmaxf(bx[1], bx[3]), fmaxf(bx[5], bx[7]));
        float sx1 = xmn * 0.25f, sy1 = ymn * 0.25f;
        float sx2 = xmx * 0.25f, sy2 = ymx * 0.25f;
        float rw = fmaxf(sx2 - sx1, 1.0f), rh = fmaxf(sy2 - sy1, 1.0f);
        float binw = rw * (1.0f / 3.0f), binh = rh * (1.0f / 3.0f);
        int row = t / 6, col = t % 6;
        float y = sy1 + (row * 0.5f + 0.25f) * binh;
        float x = sx1 + (col * 0.5f + 0.25f) * binw;
        float valid = (y > -1.0f && y < 256.0f && x > -1.0f && x < 256.0f) ? 1.0f : 0.0f;
        y = fminf(fmaxf(y, 0.0f), 255.0f);
        x = fminf(fmaxf(x, 0.0f), 255.0f);
        int y0 = (int)floorf(y), x0 = (int)floorf(x);
        int y1 = min(y0 + 1, 255), x1 = min(x0 + 1, 255);
        float ly = y - (float)y0, lx = x - (float)x0;
        float hy = 1.0f - ly, hx = 1.0f - lx;
        float m = 0.25f * valid;
        so[t][0] = y0 * HW_ + x0;  so[t][1] = y0 * HW_ + x1;
        so[t][2] = y1 * HW_ + x0;  so[t][3] = y1 * HW_ + x1;
        sw[t][0] = hy * hx * m;    sw[t][1] = hy * lx * m;
        sw[t][2] = ly * hx * m;    sw[t][3] = ly * lx * m;
    }
    __syncthreads();

    const float* base = feats + ((size_t)(b * CIN_ + t) << 16);
    float acc[9] = {0.f,0.f,0.f,0.f,0.f,0.f,0.f,0.f,0.f};
    #pragma unroll
    for (int j = 0; j < 36; ++j) {
        const int bin = ((j / 6) >> 1) * 3 + ((j % 6) >> 1);
        float v = sw[j][0] * base[so[j][0]] + sw[j][1] * base[so[j][1]]
                + sw[j][2] * base[so[j][2]] + sw[j][3] * base[so[j][3]];
        acc[bin] += v;
    }
    unsigned short* dst = flat + (size_t)bn * INK_ + t * 9;
    #pragma unroll
    for (int k = 0; k < 9; ++k) dst[k] = f2bf(acc[k]);
}

template <int K, bool RELU_BF16OUT>
__global__ __launch_bounds__(256) void k_gemm(
    const unsigned short* __restrict__ A,
    const unsigned short* __restrict__ Bt,
    const float* __restrict__ bias,
    unsigned short* __restrict__ Cbf,
    float* __restrict__ Cf)
{
    __shared__ __align__(16) unsigned short Asl[64 * 40];
    __shared__ __align__(16) unsigned short Bsl[64 * 40];

    const int t  = threadIdx.x;
    const int m0 = blockIdx.x * 64;
    const int n0 = blockIdx.y * 64;
    const int w  = t >> 6;
    const int l  = t & 63;
    const int lane16 = l & 15;
    const int q  = l >> 4;

    f32x4 acc[4] = {};

    const int srow = t >> 2;
    const int sch  = t & 3;
    const unsigned short* ga = A  + (size_t)(m0 + srow) * K + sch * 8;
    const unsigned short* gb = Bt + (size_t)(n0 + srow) * K + sch * 8;
    unsigned short* la = &Asl[srow * 40 + sch * 8];
    unsigned short* lb = &Bsl[srow * 40 + sch * 8];

    for (int k0 = 0; k0 < K; k0 += 32) {
        __syncthreads();
        *(bf16x8*)la = *(const bf16x8*)(ga + k0);
        *(bf16x8*)lb = *(const bf16x8*)(gb + k0);
        __syncthreads();
        bf16x8 af = *(const bf16x8*)&Asl[(w * 16 + lane16) * 40 + q * 8];
        #pragma unroll
        for (int nt = 0; nt < 4; ++nt) {
            bf16x8 bfv = *(const bf16x8*)&Bsl[(nt * 16 + lane16) * 40 + q * 8];
            acc[nt] = __builtin_amdgcn_mfma_f32_16x16x32_bf16(af, bfv, acc[nt], 0, 0, 0);
        }
    }

    #pragma unroll
    for (int nt = 0; nt < 4; ++nt) {
        int col = n0 + nt * 16 + lane16;
        float bs = bias[col];
        #pragma unroll
        for (int r = 0; r < 4; ++r) {
            int rowg = m0 + w * 16 + q * 4 + r;
            float v = acc[nt][r] + bs;
            if constexpr (RELU_BF16OUT) {
                v = fmaxf(v, 0.0f);
                Cbf[(size_t)rowg * D_ + col] = f2bf(v);
            } else {
                Cf[(size_t)rowg * D_ + col] = v;
            }
        }
    }
}

__device__ __forceinline__ void breduce2(float& a, float& b, float* red, int t) {
    #pragma unroll
    for (int off = 32; off > 0; off >>= 1) {
        a += __shfl_down(a, off);
        b += __shfl_down(b, off);
    }
    int w = t >> 6;
    if ((t & 63) == 0) { red[w] = a; red[4 + w] = b; }
    __syncthreads();
    a = red[0] + red[1] + red[2] + red[3];
    b = red[4] + red[5] + red[6] + red[7];
    __syncthreads();
}

__global__ __launch_bounds__(256) void k_tail(
    const float* __restrict__ lines, const float* __restrict__ boxes,
    const float* __restrict__ img_sizes,
    const float* __restrict__ Wb,  const float* __restrict__ bbv,
    const float* __restrict__ g1,  const float* __restrict__ be1,
    const float* __restrict__ g2,  const float* __restrict__ be2,
    float* __restrict__ out)
{
    __shared__ float red[8];
    const int row = blockIdx.x;
    const int b = row >> 10, n = row & 1023;
    const int t = threadIdx.x;

    const float* bx = boxes + (size_t)row * 8;
    float xmn = fminf(fminf(bx[0], bx[2]), fminf(bx[4], bx[6]));
    float xmx = fmaxf(fmaxf(bx[0], bx[2]), fmaxf(bx[4], bx[6]));
    float ymn = fminf(fminf(bx[1], bx[3]), fminf(bx[5], bx[7]));
    float ymx = fmaxf(fmaxf(bx[1], bx[3]), fmaxf(bx[5], bx[7]));
    float s0 = img_sizes[b * 2], s1 = img_sizes[b * 2 + 1];
    float q0 = xmn / s0, q1 = ymn / s1, q2 = xmx / s0, q3 = ymx / s1;

    float tv[2], sv[2];
    float sum = 0.f, sumsq = 0.f;
    #pragma unroll
    for (int i = 0; i < 2; ++i) {
        int d = t + i * 256;
        float v = q0 * Wb[d] + q1 * Wb[512 + d] + q2 * Wb[1024 + d] + q3 * Wb[1536 + d] + bbv[d];
        tv[i] = v; sum += v; sumsq += v * v;
    }
    breduce2(sum, sumsq, red, t);
    float mu = sum * (1.0f / 512.0f);
    float var = sumsq * (1.0f / 512.0f) - mu * mu;
    float rs = rsqrtf(var + 1e-5f);

    sum = 0.f; sumsq = 0.f;
    #pragma unroll
    for (int i = 0; i < 2; ++i) {
        int d = t + i * 256;
        float p = (tv[i] - mu) * rs * g1[d] + be1[d];
        float s = lines[(size_t)row * D_ + d] + p;
        sv[i] = s; sum += s; sumsq += s * s;
    }
    breduce2(sum, sumsq, red, t);
    float mu2 = sum * (1.0f / 512.0f);
    float var2 = sumsq * (1.0f / 512.0f) - mu2 * mu2;
    float rs2 = rsqrtf(var2 + 1e-5f);

    #pragma unroll
    for (int i = 0; i < 2; ++i) {
        int d = t + i * 256;
        float o = (sv[i] - mu2) * rs2 * g2[d] + be2[d];
        out[(size_t)b * (D_ * N_) + (size_t)d * N_ + n] = o;
    }
}

__global__ __launch_bounds__(256) void k_mask(float* __restrict__ out) {
    int i = blockIdx.x * 256 + threadIdx.x;
    if (i < B_ * 32 * 32) out[(size_t)B_ * D_ * N_ + i] = 1.0f;
}

// ---------------------------------------------------------------------------
extern "C" void kernel_launch(void* const* d_in, const int* in_sizes, int n_in,
                              void* d_out, int out_size, void* d_ws, size_t ws_size,
                              hipStream_t stream)
{
    const float* feats = (const float*)d_in[0];
    const float* boxes = (const float*)d_in[1];
    const float* img   = (const float*)d_in[2];
    const float* W1    = (const float*)d_in[3];
    const float* b1    = (const float*)d_in[4];
    const float* W2    = (const float*)d_in[5];
    const float* b2    = (const float*)d_in[6];
    const float* Wb    = (const float*)d_in[7];
    const float* bbv   = (const float*)d_in[8];
    const float* g1    = (const float*)d_in[9];
    const float* be1   = (const float*)d_in[10];
    const float* g2    = (const float*)d_in[11];
    const float* be2   = (const float*)d_in[12];
    float* out = (float*)d_out;
    char* ws = (char*)d_ws;

    // Fast-path ws layout (bytes):
    const size_t OFF_FEATST = 0;                         // bf16 4x65536x256 = 134,217,728
    const size_t OFF_W1T    = 134217728;                 // bf16 512x2304   =   2,359,296
    const size_t OFF_W2T    = 136577024;                 // bf16 512x512    =     524,288
    const size_t OFF_FLAT   = 137101312;                 // bf16 4096x2304  =  18,874,368
    const size_t OFF_ACT    = 155975680;                 // bf16 4096x512   =   4,194,304
    const size_t NEED       = 160169984;

    if (ws_size >= NEED) {
        unsigned short* featsT = (unsigned short*)(ws + OFF_FEATST);
        unsigned short* W1t    = (unsigned short*)(ws + OFF_W1T);
        unsigned short* W2t    = (unsigned short*)(ws + OFF_W2T);
        unsigned short* flat   = (unsigned short*)(ws + OFF_FLAT);
        unsigned short* act    = (unsigned short*)(ws + OFF_ACT);

        // === ATTRIBUTION: each kernel launched 2x (idempotent). ===
        k_t64f<<<dim3(HW_*HW_/64, CIN_/64, B_), 256, 0, stream>>>(feats, featsT);
        k_t64f<<<dim3(HW_*HW_/64, CIN_/64, B_), 256, 0, stream>>>(feats, featsT);

        k_t64w<<<dim3(D_/64, 44), 256, 0, stream>>>(W1, W2, W1t, W2t);
        k_t64w<<<dim3(D_/64, 44), 256, 0, stream>>>(W1, W2, W1t, W2t);

        k_roi5<<<BN_/2, 256, 0, stream>>>(featsT, boxes, flat);
        k_roi5<<<BN_/2, 256, 0, stream>>>(featsT, boxes, flat);

        dim3 gg(64, 8);
        k_gemmB64<INK_, true><<<gg, 256, 0, stream>>>(flat, W1t, b1, act, nullptr);
        k_gemmB64<INK_, true><<<gg, 256, 0, stream>>>(flat, W1t, b1, act, nullptr);

        k_fuse2<<<BN_/16, 256, 0, stream>>>(act, W2t, b2, boxes, img,
                                            Wb, bbv, g1, be1, g2, be2, out);
        k_fuse2<<<BN_/16, 256, 0, stream>>>(act, W2t, b2, boxes, img,
                                            Wb, bbv, g1, be1, g2, be2, out);
    } else {
        // Fallback: round-1 path
        unsigned short* W1t  = (unsigned short*)(ws);
        unsigned short* W2t  = (unsigned short*)(ws + 2359296);
        unsigned short* flat = (unsigned short*)(ws + 2883584);
        unsigned short* act  = (unsigned short*)(ws + 21757952);
        float*          lines= (float*)(ws + 25952256);

        const int convTotal = INK_ * D_ + D_ * D_;
        k_convert<<<(convTotal + 255) / 256, 256, 0, stream>>>(W1, W2, W1t, W2t);
        k_roi<<<BN_, 256, 0, stream>>>(feats, boxes, flat);
        dim3 gg(64, 8);
        k_gemm<INK_, true ><<<gg, 256, 0, stream>>>(flat, W1t, b1, act, nullptr);
        k_gemm<D_,   false><<<gg, 256, 0, stream>>>(act,  W2t, b2, nullptr, lines);
        k_tail<<<BN_, 256, 0, stream>>>(lines, boxes, img, Wb, bbv, g1, be1, g2, be2, out);
        k_mask<<<16, 256, 0, stream>>>(out);
    }
}

// Round 7
// 503.817 us; speedup vs baseline: 1.3479x; 1.3479x over previous
//
#include <hip/hip_runtime.h>
#include <hip/hip_bf16.h>
#include <cstdint>
#include <cstddef>

// Problem constants
#define B_    4
#define N_    1024
#define CIN_  256
#define HW_   256      // H == W == 256
#define D_    512
#define INK_  2304     // CIN * PH * PW
#define BN_   4096     // B * N

typedef __attribute__((ext_vector_type(8))) short bf16x8;
typedef __attribute__((ext_vector_type(4))) float f32x4;
typedef __attribute__((ext_vector_type(4))) unsigned short us4;
typedef __attribute__((ext_vector_type(8))) unsigned short us8;

#define AS1(p) ((const __attribute__((address_space(1))) void*)(p))
#define AS3(p) ((__attribute__((address_space(3))) void*)(p))

__device__ __forceinline__ unsigned short f2bf(float f) {
    union { float f; unsigned u; } v; v.f = f;
    unsigned r = v.u + 0x7fffu + ((v.u >> 16) & 1u);   // round-to-nearest-even
    return (unsigned short)(r >> 16);
}

// ---------------------------------------------------------------------------
// 64x64 tile transpose body: src fp32 (Mrows, Ncols) -> dst bf16 (Ncols, Mrows)
// Store phase uses 16 B us8 stores (2 per thread) to halve write-instruction
// count on the 128 MB featsT stream.
// ---------------------------------------------------------------------------
__device__ __forceinline__ void t64_body(
    const float* __restrict__ src, unsigned short* __restrict__ dst,
    int Mrows, int Ncols, int m0, int n0, int t,
    unsigned short (*tile)[66])
{
    const int rr = t >> 4;          // 0..15
    const int cc = t & 15;          // 0..15

    #pragma unroll
    for (int i = 0; i < 4; ++i) {
        int row = i * 16 + rr;
        float4 v = *(const float4*)(src + (size_t)(m0 + row) * Ncols + n0 + cc * 4);
        tile[row][cc * 4 + 0] = f2bf(v.x);
        tile[row][cc * 4 + 1] = f2bf(v.y);
        tile[row][cc * 4 + 2] = f2bf(v.z);
        tile[row][cc * 4 + 3] = f2bf(v.w);
    }
    __syncthreads();
    // 64 px x 8 chunks (8 ch = 16 B) = 512 units over 256 threads.
    #pragma unroll
    for (int i = 0; i < 2; ++i) {
        int u  = t + i * 256;
        int p  = u >> 3;            // pixel within tile
        int c8 = (u & 7) * 8;       // channel chunk
        us8 v;
        #pragma unroll
        for (int k = 0; k < 8; ++k) v[k] = tile[c8 + k][p];
        *(us8*)(dst + (size_t)(n0 + p) * Mrows + m0 + c8) = v;
    }
}

// Merged transpose launch: grid (1024, 4, 5).
//   z<4 : feats (B,CIN,HW*HW) f32 -> featsT (B,HW*HW,CIN) bf16, batch z.
//   z==4: flat idx = y*1024+x; idx<288 -> W1 tile; 288..351 -> W2 tile.
__global__ __launch_bounds__(256) void k_t64all(
    const float* __restrict__ feats, unsigned short* __restrict__ featsT,
    const float* __restrict__ W1, const float* __restrict__ W2,
    unsigned short* __restrict__ W1t, unsigned short* __restrict__ W2t)
{
    __shared__ unsigned short tile[64][66];
    if (blockIdx.z < 4) {
        const size_t batch = (size_t)CIN_ * HW_ * HW_;
        t64_body(feats + blockIdx.z * batch, featsT + blockIdx.z * batch,
                 CIN_, HW_ * HW_, blockIdx.y * 64, blockIdx.x * 64,
                 threadIdx.x, tile);
    } else {
        const int idx = blockIdx.y * 1024 + blockIdx.x;
        if (idx < 288) {            // W1 (2304,512) -> W1t (512,2304)
            t64_body(W1, W1t, INK_, D_, (idx >> 3) * 64, (idx & 7) * 64,
                     threadIdx.x, tile);
        } else if (idx < 352) {     // W2 (512,512) -> W2t (512,512)
            const int j = idx - 288;
            t64_body(W2, W2t, D_, D_, (j >> 3) * 64, (j & 7) * 64,
                     threadIdx.x, tile);
        }
    }
}

// ---------------------------------------------------------------------------
// ROI-align gather (roi5): block = 2 boxes x 4 waves; sample-halves split
// across 32-lane halves, combined via __shfl_xor(.,32).
// ---------------------------------------------------------------------------
__global__ __launch_bounds__(256) void k_roi5(
    const unsigned short* __restrict__ featsT, const float* __restrict__ boxes,
    unsigned short* __restrict__ flat)
{
    __shared__ int   so[2][36][4];
    __shared__ float sw[2][36][4];
    const int t = threadIdx.x;

    if (t < 72) {
        const int mbx = t / 36, s = t - mbx * 36;
        const int mbn = blockIdx.x * 2 + mbx;
        const float* bx = boxes + (size_t)mbn * 8;
        float xmn = fminf(fminf(bx[0], bx[2]), fminf(bx[4], bx[6]));
        float xmx = fmaxf(fmaxf(bx[0], bx[2]), fmaxf(bx[4], bx[6]));
        float ymn = fminf(fminf(bx[1], bx[3]), fminf(bx[5], bx[7]));
        float ymx = fmaxf(fmaxf(bx[1], bx[3]), fmaxf(bx[5], bx[7]));
        float sx1 = xmn * 0.25f, sy1 = ymn * 0.25f;
        float sx2 = xmx * 0.25f, sy2 = ymx * 0.25f;
        float rw = fmaxf(sx2 - sx1, 1.0f), rh = fmaxf(sy2 - sy1, 1.0f);
        float binw = rw * (1.0f / 3.0f), binh = rh * (1.0f / 3.0f);
        int row = s / 6, col = s % 6;
        float y = sy1 + (row * 0.5f + 0.25f) * binh;
        float x = sx1 + (col * 0.5f + 0.25f) * binw;
        float valid = (y > -1.0f && y < 256.0f && x > -1.0f && x < 256.0f) ? 1.0f : 0.0f;
        y = fminf(fmaxf(y, 0.0f), 255.0f);
        x = fminf(fmaxf(x, 0.0f), 255.0f);
        int y0 = (int)floorf(y), x0 = (int)floorf(x);
        int y1 = min(y0 + 1, 255), x1 = min(x0 + 1, 255);
        float ly = y - (float)y0, lx = x - (float)x0;
        float hy = 1.0f - ly, hx = 1.0f - lx;
        float m = 0.25f * valid;
        so[mbx][s][0] = y0 * HW_ + x0;  so[mbx][s][1] = y0 * HW_ + x1;
        so[mbx][s][2] = y1 * HW_ + x0;  so[mbx][s][3] = y1 * HW_ + x1;
        sw[mbx][s][0] = hy * hx * m;    sw[mbx][s][1] = hy * lx * m;
        sw[mbx][s][2] = ly * hx * m;    sw[mbx][s][3] = ly * lx * m;
    }
    __syncthreads();

    const int w    = t >> 6;
    const int l    = t & 63;
    const int bxi  = w >> 1;
    const int half = w & 1;
    const int qd   = half * 32 + (l & 31);
    const int sh   = l >> 5;
    const int j0   = sh * 18;
    const int bn   = blockIdx.x * 2 + bxi;
    const int b    = bn >> 10;
    const uint2* basep = (const uint2*)featsT + (size_t)b * (65536ull * 64ull) + qd;

    float a0[9] = {0,0,0,0,0,0,0,0,0};
    float a1[9] = {0,0,0,0,0,0,0,0,0};
    float a2[9] = {0,0,0,0,0,0,0,0,0};
    float a3[9] = {0,0,0,0,0,0,0,0,0};
    #pragma unroll
    for (int jj = 0; jj < 18; ++jj) {
        const int j = j0 + jj;
        #pragma unroll
        for (int p = 0; p < 4; ++p) {
            float wgt = sw[bxi][j][p];
            uint2 u = basep[(size_t)so[bxi][j][p] << 6];
            const int binA = (( jj / 6      ) >> 1) * 3 + ((jj % 6) >> 1);  // sh=0
            const int binB = (((jj / 6) + 3 ) >> 1) * 3 + ((jj % 6) >> 1);  // sh=1
            const int bs = sh ? binB : binA;
            a0[bs] += wgt * __uint_as_float(u.x << 16);
            a1[bs] += wgt * __uint_as_float(u.x & 0xffff0000u);
            a2[bs] += wgt * __uint_as_float(u.y << 16);
            a3[bs] += wgt * __uint_as_float(u.y & 0xffff0000u);
        }
    }

    #pragma unroll
    for (int k = 0; k < 9; ++k) {
        a0[k] += __shfl_xor(a0[k], 32);
        a1[k] += __shfl_xor(a1[k], 32);
        a2[k] += __shfl_xor(a2[k], 32);
        a3[k] += __shfl_xor(a3[k], 32);
    }

    unsigned short lo9[9], hi9[9];
    #pragma unroll
    for (int k = 0; k < 9; ++k) {
        lo9[k] = f2bf(sh ? a2[k] : a0[k]);
        hi9[k] = f2bf(sh ? a3[k] : a1[k]);
    }
    unsigned short s18[18];
    #pragma unroll
    for (int k = 0; k < 9; ++k) { s18[k] = lo9[k]; s18[9 + k] = hi9[k]; }
    unsigned* dst = (unsigned*)(flat + (size_t)bn * INK_) + qd * 18 + sh * 9;
    #pragma unroll
    for (int k = 0; k < 9; ++k)
        dst[k] = (unsigned)s18[2 * k] | ((unsigned)s18[2 * k + 1] << 16);
}

// ---------------------------------------------------------------------------
// GEMM1: 64x64 tile, BK=32, global_load_lds dbuf, T2 chunk swizzle.
// ---------------------------------------------------------------------------
template <int K, bool RELU_BF16OUT>
__global__ __launch_bounds__(256) void k_gemmB64(
    const unsigned short* __restrict__ A,
    const unsigned short* __restrict__ Bt,
    const float* __restrict__ bias,
    unsigned short* __restrict__ Cbf,
    float* __restrict__ Cf)
{
    __shared__ __align__(16) unsigned short As[2][64 * 32];
    __shared__ __align__(16) unsigned short Bs[2][64 * 32];

    const int t = threadIdx.x;
    const int w = t >> 6;
    const int lane = t & 63;
    const int lane16 = lane & 15;
    const int q = lane >> 4;
    const int m0 = blockIdx.x * 64;
    const int n0 = blockIdx.y * 64;

    const int srow = t >> 2;
    const int c4s  = (t & 3) ^ ((t >> 4) & 3);
    const unsigned short* gA = A  + (size_t)(m0 + srow) * K + c4s * 8;
    const unsigned short* gB = Bt + (size_t)(n0 + srow) * K + c4s * 8;
    const int ldst = srow * 32 + (t & 3) * 8;

    const int qs = q ^ ((lane16 >> 2) & 3);

    f32x4 acc[4] = {};

    __builtin_amdgcn_global_load_lds(AS1(gA), AS3(&As[0][0] + ldst), 16, 0, 0);
    __builtin_amdgcn_global_load_lds(AS1(gB), AS3(&Bs[0][0] + ldst), 16, 0, 0);
    gA += 32; gB += 32;

    int cur = 0;
    for (int k0 = 0; k0 < K; k0 += 32) {
        __syncthreads();
        if (k0 + 32 < K) {
            __builtin_amdgcn_global_load_lds(AS1(gA), AS3(&As[cur ^ 1][0] + ldst), 16, 0, 0);
            __builtin_amdgcn_global_load_lds(AS1(gB), AS3(&Bs[cur ^ 1][0] + ldst), 16, 0, 0);
            gA += 32; gB += 32;
        }
        bf16x8 av = *(const bf16x8*)&As[cur][(w * 16 + lane16) * 32 + qs * 8];
        #pragma unroll
        for (int nt = 0; nt < 4; ++nt) {
            bf16x8 bv = *(const bf16x8*)&Bs[cur][(nt * 16 + lane16) * 32 + qs * 8];
            acc[nt] = __builtin_amdgcn_mfma_f32_16x16x32_bf16(av, bv, acc[nt], 0, 0, 0);
        }
        cur ^= 1;
    }

    #pragma unroll
    for (int nt = 0; nt < 4; ++nt) {
        int col = n0 + nt * 16 + lane16;
        float bs = bias[col];
        #pragma unroll
        for (int r = 0; r < 4; ++r) {
            int row = m0 + w * 16 + q * 4 + r;
            float v = acc[nt][r] + bs;
            if constexpr (RELU_BF16OUT) {
                v = fmaxf(v, 0.0f);
                Cbf[(size_t)row * D_ + col] = f2bf(v);
            } else {
                Cf[(size_t)row * D_ + col] = v;
            }
        }
    }
}

// ---------------------------------------------------------------------------
// Fused GEMM2 + bias + pos-matvec + LN1 + add + LN2 + transposed store + mask.
// ---------------------------------------------------------------------------
__global__ __launch_bounds__(256) void k_fuse2(
    const unsigned short* __restrict__ act,
    const unsigned short* __restrict__ W2t,
    const float* __restrict__ b2,
    const float* __restrict__ boxes,
    const float* __restrict__ img_sizes,
    const float* __restrict__ Wb,  const float* __restrict__ bbv,
    const float* __restrict__ g1,  const float* __restrict__ be1,
    const float* __restrict__ g2,  const float* __restrict__ be2,
    float* __restrict__ out)
{
    __shared__ float S2[16 * D_];    // 32 KB

    const int t = threadIdx.x;
    const int w = t >> 6, l = t & 63;
    const int lane16 = l & 15, q = l >> 4;
    const int m0 = blockIdx.x * 16;
    const int b  = m0 >> 10;

    f32x4 acc[8] = {};
    const unsigned short* gA = act + (size_t)(m0 + lane16) * D_ + q * 8;
    const unsigned short* gW = W2t + (size_t)(w * 128 + lane16) * D_ + q * 8;

    #pragma unroll 2
    for (int k0 = 0; k0 < D_; k0 += 32) {
        bf16x8 av = *(const bf16x8*)(gA + k0);
        #pragma unroll
        for (int nt = 0; nt < 8; ++nt) {
            bf16x8 bv = *(const bf16x8*)(gW + (size_t)(nt * 16) * D_ + k0);
            acc[nt] = __builtin_amdgcn_mfma_f32_16x16x32_bf16(av, bv, acc[nt], 0, 0, 0);
        }
    }

    #pragma unroll
    for (int nt = 0; nt < 8; ++nt) {
        int col = w * 128 + nt * 16 + lane16;
        float bs = b2[col];
        #pragma unroll
        for (int r = 0; r < 4; ++r)
            S2[(q * 4 + r) * D_ + col] = acc[nt][r] + bs;
    }
    __syncthreads();

    const float si0 = img_sizes[b * 2], si1 = img_sizes[b * 2 + 1];
    #pragma unroll 1
    for (int j = 0; j < 4; ++j) {
        const int rho = w * 4 + j;
        const float* bx = boxes + (size_t)(m0 + rho) * 8;
        float xmn = fminf(fminf(bx[0], bx[2]), fminf(bx[4], bx[6]));
        float xmx = fmaxf(fmaxf(bx[0], bx[2]), fmaxf(bx[4], bx[6]));
        float ymn = fminf(fminf(bx[1], bx[3]), fminf(bx[5], bx[7]));
        float ymx = fmaxf(fmaxf(bx[1], bx[3]), fmaxf(bx[5], bx[7]));
        float q0 = xmn / si0, q1 = ymn / si1, q2 = xmx / si0, q3 = ymx / si1;

        float tp[8], su = 0.f, sq = 0.f;
        #pragma unroll
        for (int i = 0; i < 8; ++i) {
            int d = i * 64 + l;
            float v = q0 * Wb[d] + q1 * Wb[512 + d] + q2 * Wb[1024 + d]
                    + q3 * Wb[1536 + d] + bbv[d];
            tp[i] = v; su += v; sq += v * v;
        }
        #pragma unroll
        for (int off = 32; off > 0; off >>= 1) {
            su += __shfl_xor(su, off); sq += __shfl_xor(sq, off);
        }
        float mu = su * (1.0f / 512.0f);
        float rs = rsqrtf(sq * (1.0f / 512.0f) - mu * mu + 1e-5f);

        float sv[8]; su = 0.f; sq = 0.f;
        #pragma unroll
        for (int i = 0; i < 8; ++i) {
            int d = i * 64 + l;
            float p = (tp[i] - mu) * rs * g1[d] + be1[d];
            float s = S2[rho * D_ + d] + p;
            sv[i] = s; su += s; sq += s * s;
        }
        #pragma unroll
        for (int off = 32; off > 0; off >>= 1) {
            su += __shfl_xor(su, off); sq += __shfl_xor(sq, off);
        }
        float mu2 = su * (1.0f / 512.0f);
        float rs2 = rsqrtf(sq * (1.0f / 512.0f) - mu2 * mu2 + 1e-5f);

        #pragma unroll
        for (int i = 0; i < 8; ++i) {
            int d = i * 64 + l;
            S2[rho * D_ + d] = (sv[i] - mu2) * rs2 * g2[d] + be2[d];
        }
    }
    __syncthreads();

    const int nb = m0 & 1023;
    float* ob = out + (size_t)b * (D_ * N_) + nb;
    const int dd = t >> 2, part = t & 3;
    #pragma unroll
    for (int i = 0; i < 8; ++i) {
        int d = i * 64 + dd;
        float4 v;
        v.x = S2[(part * 4 + 0) * D_ + d];
        v.y = S2[(part * 4 + 1) * D_ + d];
        v.z = S2[(part * 4 + 2) * D_ + d];
        v.w = S2[(part * 4 + 3) * D_ + d];
        *(float4*)(ob + (size_t)d * N_ + part * 4) = v;
    }
    if (t < 16) out[(size_t)B_ * D_ * N_ + m0 + t] = 1.0f;   // masks
}

// ---------------------------------------------------------------------------
// FALLBACK path kernels (unchanged).
// ---------------------------------------------------------------------------
__global__ __launch_bounds__(256) void k_convert(
    const float* __restrict__ W1, const float* __restrict__ W2,
    unsigned short* __restrict__ W1t, unsigned short* __restrict__ W2t)
{
    int i = blockIdx.x * 256 + threadIdx.x;
    const int n1 = INK_ * D_;
    if (i < n1) {
        int n = i / INK_, k = i % INK_;
        W1t[i] = f2bf(W1[(size_t)k * D_ + n]);
    } else {
        int j = i - n1;
        if (j < D_ * D_) {
            int n = j / D_, k = j % D_;
            W2t[j] = f2bf(W2[(size_t)k * D_ + n]);
        }
    }
}

__global__ __launch_bounds__(256) void k_roi(
    const float* __restrict__ feats, const float* __restrict__ boxes,
    unsigned short* __restrict__ flat)
{
    __shared__ int   so[36][4];
    __shared__ float sw[36][4];
    const int bn = blockIdx.x;
    const int b  = bn >> 10;
    const int t  = threadIdx.x;

    if (t < 36) {
        const float* bx = boxes + (size_t)bn * 8;
        float xmn = fminf(fminf(bx[0], bx[2]), fminf(bx[4], bx[6]));
        float xmx = fmaxf(fmaxf(bx[0], bx[2]), fmaxf(bx[4], bx[6]));
        float ymn = fminf(fminf(bx[1], bx[3]), fminf(bx[5], bx[7]));
        float ymx = fmaxf(fmaxf(bx[1], bx[3]), fmaxf(bx[5], bx[7]));
        float sx1 = xmn * 0.25f, sy1 = ymn * 0.25f;
        float sx2 = xmx * 0.25f, sy2 = ymx * 0.25f;
        float rw = fmaxf(sx2 - sx1, 1.0f), rh = fmaxf(sy2 - sy1, 1.0f);
        float binw = rw * (1.0f / 3.0f), binh = rh * (1.0f / 3.0f);
        int row = t / 6, col = t % 6;
        float y = sy1 + (row * 0.5f + 0.25f) * binh;
        float x = sx1 + (col * 0.5f + 0.25f) * binw;
        float valid = (y > -1.0f && y < 256.0f && x > -1.0f && x < 256.0f) ? 1.0f : 0.0f;
        y = fminf(fmaxf(y, 0.0f), 255.0f);
        x = fminf(fmaxf(x, 0.0f), 255.0f);
        int y0 = (int)floorf(y), x0 = (int)floorf(x);
        int y1 = min(y0 + 1, 255), x1 = min(x0 + 1, 255);
        float ly = y - (float)y0, lx = x - (float)x0;
        float hy = 1.0f - ly, hx = 1.0f - lx;
        float m = 0.25f * valid;
        so[t][0] = y0 * HW_ + x0;  so[t][1] = y0 * HW_ + x1;
        so[t][2] = y1 * HW_ + x0;  so[t][3] = y1 * HW_ + x1;
        sw[t][0] = hy * hx * m;    sw[t][1] = hy * lx * m;
        sw[t][2] = ly * hx * m;    sw[t][3] = ly * lx * m;
    }
    __syncthreads();

    const float* base = feats + ((size_t)(b * CIN_ + t) << 16);
    float acc[9] = {0.f,0.f,0.f,0.f,0.f,0.f,0.f,0.f,0.f};
    #pragma unroll
    for (int j = 0; j < 36; ++j) {
        const int bin = ((j / 6) >> 1) * 3 + ((j % 6) >> 1);
        float v = sw[j][0] * base[so[j][0]] + sw[j][1] * base[so[j][1]]
                + sw[j][2] * base[so[j][2]] + sw[j][3] * base[so[j][3]];
        acc[bin] += v;
    }
    unsigned short* dst = flat + (size_t)bn * INK_ + t * 9;
    #pragma unroll
    for (int k = 0; k < 9; ++k) dst[k] = f2bf(acc[k]);
}

template <int K, bool RELU_BF16OUT>
__global__ __launch_bounds__(256) void k_gemm(
    const unsigned short* __restrict__ A,
    const unsigned short* __restrict__ Bt,
    const float* __restrict__ bias,
    unsigned short* __restrict__ Cbf,
    float* __restrict__ Cf)
{
    __shared__ __align__(16) unsigned short Asl[64 * 40];
    __shared__ __align__(16) unsigned short Bsl[64 * 40];

    const int t  = threadIdx.x;
    const int m0 = blockIdx.x * 64;
    const int n0 = blockIdx.y * 64;
    const int w  = t >> 6;
    const int l  = t & 63;
    const int lane16 = l & 15;
    const int q  = l >> 4;

    f32x4 acc[4] = {};

    const int srow = t >> 2;
    const int sch  = t & 3;
    const unsigned short* ga = A  + (size_t)(m0 + srow) * K + sch * 8;
    const unsigned short* gb = Bt + (size_t)(n0 + srow) * K + sch * 8;
    unsigned short* la = &Asl[srow * 40 + sch * 8];
    unsigned short* lb = &Bsl[srow * 40 + sch * 8];

    for (int k0 = 0; k0 < K; k0 += 32) {
        __syncthreads();
        *(bf16x8*)la = *(const bf16x8*)(ga + k0);
        *(bf16x8*)lb = *(const bf16x8*)(gb + k0);
        __syncthreads();
        bf16x8 af = *(const bf16x8*)&Asl[(w * 16 + lane16) * 40 + q * 8];
        #pragma unroll
        for (int nt = 0; nt < 4; ++nt) {
            bf16x8 bfv = *(const bf16x8*)&Bsl[(nt * 16 + lane16) * 40 + q * 8];
            acc[nt] = __builtin_amdgcn_mfma_f32_16x16x32_bf16(af, bfv, acc[nt], 0, 0, 0);
        }
    }

    #pragma unroll
    for (int nt = 0; nt < 4; ++nt) {
        int col = n0 + nt * 16 + lane16;
        float bs = bias[col];
        #pragma unroll
        for (int r = 0; r < 4; ++r) {
            int rowg = m0 + w * 16 + q * 4 + r;
            float v = acc[nt][r] + bs;
            if constexpr (RELU_BF16OUT) {
                v = fmaxf(v, 0.0f);
                Cbf[(size_t)rowg * D_ + col] = f2bf(v);
            } else {
                Cf[(size_t)rowg * D_ + col] = v;
            }
        }
    }
}

__device__ __forceinline__ void breduce2(float& a, float& b, float* red, int t) {
    #pragma unroll
    for (int off = 32; off > 0; off >>= 1) {
        a += __shfl_down(a, off);
        b += __shfl_down(b, off);
    }
    int w = t >> 6;
    if ((t & 63) == 0) { red[w] = a; red[4 + w] = b; }
    __syncthreads();
    a = red[0] + red[1] + red[2] + red[3];
    b = red[4] + red[5] + red[6] + red[7];
    __syncthreads();
}

__global__ __launch_bounds__(256) void k_tail(
    const float* __restrict__ lines, const float* __restrict__ boxes,
    const float* __restrict__ img_sizes,
    const float* __restrict__ Wb,  const float* __restrict__ bbv,
    const float* __restrict__ g1,  const float* __restrict__ be1,
    const float* __restrict__ g2,  const float* __restrict__ be2,
    float* __restrict__ out)
{
    __shared__ float red[8];
    const int row = blockIdx.x;
    const int b = row >> 10, n = row & 1023;
    const int t = threadIdx.x;

    const float* bx = boxes + (size_t)row * 8;
    float xmn = fminf(fminf(bx[0], bx[2]), fminf(bx[4], bx[6]));
    float xmx = fmaxf(fmaxf(bx[0], bx[2]), fmaxf(bx[4], bx[6]));
    float ymn = fminf(fminf(bx[1], bx[3]), fminf(bx[5], bx[7]));
    float ymx = fmaxf(fmaxf(bx[1], bx[3]), fmaxf(bx[5], bx[7]));
    float s0 = img_sizes[b * 2], s1 = img_sizes[b * 2 + 1];
    float q0 = xmn / s0, q1 = ymn / s1, q2 = xmx / s0, q3 = ymx / s1;

    float tv[2], sv[2];
    float sum = 0.f, sumsq = 0.f;
    #pragma unroll
    for (int i = 0; i < 2; ++i) {
        int d = t + i * 256;
        float v = q0 * Wb[d] + q1 * Wb[512 + d] + q2 * Wb[1024 + d] + q3 * Wb[1536 + d] + bbv[d];
        tv[i] = v; sum += v; sumsq += v * v;
    }
    breduce2(sum, sumsq, red, t);
    float mu = sum * (1.0f / 512.0f);
    float var = sumsq * (1.0f / 512.0f) - mu * mu;
    float rs = rsqrtf(var + 1e-5f);

    sum = 0.f; sumsq = 0.f;
    #pragma unroll
    for (int i = 0; i < 2; ++i) {
        int d = t + i * 256;
        float p = (tv[i] - mu) * rs * g1[d] + be1[d];
        float s = lines[(size_t)row * D_ + d] + p;
        sv[i] = s; sum += s; sumsq += s * s;
    }
    breduce2(sum, sumsq, red, t);
    float mu2 = sum * (1.0f / 512.0f);
    float var2 = sumsq * (1.0f / 512.0f) - mu2 * mu2;
    float rs2 = rsqrtf(var2 + 1e-5f);

    #pragma unroll
    for (int i = 0; i < 2; ++i) {
        int d = t + i * 256;
        float o = (sv[i] - mu2) * rs2 * g2[d] + be2[d];
        out[(size_t)b * (D_ * N_) + (size_t)d * N_ + n] = o;
    }
}

__global__ __launch_bounds__(256) void k_mask(float* __restrict__ out) {
    int i = blockIdx.x * 256 + threadIdx.x;
    if (i < B_ * 32 * 32) out[(size_t)B_ * D_ * N_ + i] = 1.0f;
}

// ---------------------------------------------------------------------------
extern "C" void kernel_launch(void* const* d_in, const int* in_sizes, int n_in,
                              void* d_out, int out_size, void* d_ws, size_t ws_size,
                              hipStream_t stream)
{
    const float* feats = (const float*)d_in[0];
    const float* boxes = (const float*)d_in[1];
    const float* img   = (const float*)d_in[2];
    const float* W1    = (const float*)d_in[3];
    const float* b1    = (const float*)d_in[4];
    const float* W2    = (const float*)d_in[5];
    const float* b2    = (const float*)d_in[6];
    const float* Wb    = (const float*)d_in[7];
    const float* bbv   = (const float*)d_in[8];
    const float* g1    = (const float*)d_in[9];
    const float* be1   = (const float*)d_in[10];
    const float* g2    = (const float*)d_in[11];
    const float* be2   = (const float*)d_in[12];
    float* out = (float*)d_out;
    char* ws = (char*)d_ws;

    // Fast-path ws layout (bytes):
    const size_t OFF_FEATST = 0;                         // bf16 4x65536x256 = 134,217,728
    const size_t OFF_W1T    = 134217728;                 // bf16 512x2304   =   2,359,296
    const size_t OFF_W2T    = 136577024;                 // bf16 512x512    =     524,288
    const size_t OFF_FLAT   = 137101312;                 // bf16 4096x2304  =  18,874,368
    const size_t OFF_ACT    = 155975680;                 // bf16 4096x512   =   4,194,304
    const size_t NEED       = 160169984;

    if (ws_size >= NEED) {
        unsigned short* featsT = (unsigned short*)(ws + OFF_FEATST);
        unsigned short* W1t    = (unsigned short*)(ws + OFF_W1T);
        unsigned short* W2t    = (unsigned short*)(ws + OFF_W2T);
        unsigned short* flat   = (unsigned short*)(ws + OFF_FLAT);
        unsigned short* act    = (unsigned short*)(ws + OFF_ACT);

        // Merged transpose: feats (z<4) + W1/W2 (z==4) in one launch.
        k_t64all<<<dim3(HW_*HW_/64, CIN_/64, 5), 256, 0, stream>>>(
            feats, featsT, W1, W2, W1t, W2t);

        k_roi5<<<BN_/2, 256, 0, stream>>>(featsT, boxes, flat);

        dim3 gg(64, 8);   // M/64 x N/64 = 512 blocks = 2 blocks/CU
        k_gemmB64<INK_, true><<<gg, 256, 0, stream>>>(flat, W1t, b1, act, nullptr);

        k_fuse2<<<BN_/16, 256, 0, stream>>>(act, W2t, b2, boxes, img,
                                            Wb, bbv, g1, be1, g2, be2, out);
    } else {
        // Fallback: round-1 path
        unsigned short* W1t  = (unsigned short*)(ws);
        unsigned short* W2t  = (unsigned short*)(ws + 2359296);
        unsigned short* flat = (unsigned short*)(ws + 2883584);
        unsigned short* act  = (unsigned short*)(ws + 21757952);
        float*          lines= (float*)(ws + 25952256);

        const int convTotal = INK_ * D_ + D_ * D_;
        k_convert<<<(convTotal + 255) / 256, 256, 0, stream>>>(W1, W2, W1t, W2t);
        k_roi<<<BN_, 256, 0, stream>>>(feats, boxes, flat);
        dim3 gg(64, 8);
        k_gemm<INK_, true ><<<gg, 256, 0, stream>>>(flat, W1t, b1, act, nullptr);
        k_gemm<D_,   false><<<gg, 256, 0, stream>>>(act,  W2t, b2, nullptr, lines);
        k_tail<<<BN_, 256, 0, stream>>>(lines, boxes, img, Wb, bbv, g1, be1, g2, be2, out);
        k_mask<<<16, 256, 0, stream>>>(out);
    }
}